// Round 11
// baseline (3071.680 us; speedup 1.0000x reference)
//
#include <hip/hip_runtime.h>
#include <math.h>

#define NN 50000
#define NE 800000

typedef short bf8 __attribute__((ext_vector_type(8)));
typedef short bf4v __attribute__((ext_vector_type(4)));
typedef short bf2v __attribute__((ext_vector_type(2)));
typedef float f4 __attribute__((ext_vector_type(4)));

// per-wave phase fence: compiler memory barrier + hw drain (no block sync)
#define FENCE() do { __asm__ __volatile__("" ::: "memory"); \
                     __builtin_amdgcn_s_waitcnt(0); \
                     __asm__ __volatile__("" ::: "memory"); } while (0)

__device__ __forceinline__ short f2b(float f) {
  unsigned int u = __float_as_uint(f);
  unsigned int r = (u + 0x7FFFu + ((u >> 16) & 1u)) >> 16;
  return (short)(unsigned short)r;
}
__device__ __forceinline__ float b2f(short s) {
  return __uint_as_float(((unsigned int)(unsigned short)s) << 16);
}
__device__ __forceinline__ f4 b2f4(bf4v p) {
  f4 v;
  v[0] = b2f(p[0]); v[1] = b2f(p[1]); v[2] = b2f(p[2]); v[3] = b2f(p[3]);
  return v;
}

// ---------------- weight transpose + bf16 convert -----------------------------
__global__ __launch_bounds__(256) void wt_k(const float* __restrict__ in,
                                            short* __restrict__ out,
                                            int K, int N) {
  int i = blockIdx.x * 256 + threadIdx.x;
  if (i >= K * N) return;
  int n = i / K, k = i - n * K;
  out[i] = f2b(in[(size_t)k * N + n]);
}

__global__ __launch_bounds__(256) void cvt_k(const float* __restrict__ in,
                                             short* __restrict__ out, int n4) {
  int i = blockIdx.x * 256 + threadIdx.x;
  if (i >= n4) return;
  f4 v = *(const f4*)&in[(size_t)i * 4];
  bf4v p;
  p[0] = f2b(v[0]); p[1] = f2b(v[1]); p[2] = f2b(v[2]); p[3] = f2b(v[3]);
  *(bf4v*)&out[(size_t)i * 4] = p;
}

// ---------------- per-node inverse norms --------------------------------------
__global__ __launch_bounds__(256) void norm1_k(const short* __restrict__ nfb,
                                               float* __restrict__ invn) {
  const int node = blockIdx.x * 4 + (threadIdx.x >> 6);
  if (node >= NN) return;
  const int lane = threadIdx.x & 63;
  bf2v hb = *(const bf2v*)&nfb[(size_t)node * 128 + lane * 2];
  float h0 = b2f(hb[0]), h1v = b2f(hb[1]);
  float ss = fmaf(h0, h0, h1v * h1v);
#pragma unroll
  for (int o = 32; o >= 1; o >>= 1) ss += __shfl_xor(ss, o);
  if (lane == 0) invn[node] = 1.f / fmaxf(sqrtf(ss), 1e-12f);
}

__global__ __launch_bounds__(256) void norm2_k(const short* __restrict__ h1b,
                                               float* __restrict__ invn) {
  const int node = blockIdx.x * 4 + (threadIdx.x >> 6);
  if (node >= NN) return;
  const int lane = threadIdx.x & 63;
  f4 h = b2f4(*(const bf4v*)&h1b[(size_t)node * 256 + lane * 4]);
  float ss = 0.f;
#pragma unroll
  for (int r = 0; r < 4; ++r) ss = fmaf(h[r], h[r], ss);
#pragma unroll
  for (int o = 32; o >= 1; o >>= 1) ss += __shfl_xor(ss, o);
  if (lane == 0) invn[node] = 1.f / fmaxf(sqrtf(ss), 1e-12f);
}

// ---------------- degree count -------------------------------------------------
__global__ __launch_bounds__(256) void cnt_k(const int* __restrict__ dst,
                                             int* __restrict__ cnt) {
  int e = blockIdx.x * 256 + threadIdx.x;
  if (e >= NE) return;
  atomicAdd(&cnt[dst[e]], 1);
}

// ---------------- counting-sort by dst ----------------------------------------
__global__ __launch_bounds__(1024) void scan_k(const int* __restrict__ cnt,
                                               int* __restrict__ off2) {
  __shared__ int buf[1024];
  __shared__ int carry_s;
  const int t = threadIdx.x;
  if (t == 0) carry_s = 0;
  __syncthreads();
  const int nch = (NN + 1023) / 1024;
  for (int ch = 0; ch < nch; ++ch) {
    const int i = ch * 1024 + t;
    const int v = (i < NN) ? cnt[i] : 0;
    buf[t] = v;
    __syncthreads();
#pragma unroll
    for (int o = 1; o < 1024; o <<= 1) {
      int x = (t >= o) ? buf[t - o] : 0;
      __syncthreads();
      buf[t] += x;
      __syncthreads();
    }
    const int incl = buf[t];
    const int carry = carry_s;
    if (i < NN) off2[i] = carry + incl - v;
    __syncthreads();
    if (t == 1023) carry_s = carry + incl;
    __syncthreads();
  }
}

__global__ __launch_bounds__(256) void perm_k(const int* __restrict__ dst,
                                              int* __restrict__ off2,
                                              int* __restrict__ perm,
                                              int* __restrict__ dsts) {
  int e = blockIdx.x * 256 + threadIdx.x;
  if (e >= NE) return;
  int d = dst[e];
  int p = atomicAdd(&off2[d], 1);
  perm[p] = e;
  dsts[p] = d;
}

// ---------------- edge-MLP layer 1: wave-private, barrier-free ----------------
// Each wave owns 16 edges; LDS slab 16x136 bf16 (m/T/R in place). No barriers.

__global__ __launch_bounds__(256, 5) void edge_mlp1(
    const short* __restrict__ nfb, const float* __restrict__ ef,
    const int* __restrict__ src, const int* __restrict__ perm,
    const int* __restrict__ dsts, const float* __restrict__ invn1,
    const float* __restrict__ We1, const float* __restrict__ be1,
    const short* __restrict__ WaT, const float* __restrict__ ba,
    const short* __restrict__ WbT, const float* __restrict__ bbv,
    float* __restrict__ s1)
{
  __shared__ __align__(16) short U[4 * 16 * 136];   // 17408 B, 4352 B/wave
  const int t = threadIdx.x;
  const int lane = t & 63, wv = t >> 6;
  const int lr = lane & 15, lq = lane >> 4;
  short* Uw = U + wv * (16 * 136);
  const int ew0 = blockIdx.x * 64 + wv * 16;

  // per-lane metadata for edge (lane&15) -- replicated loads, L1 broadcast
  const int pe = perm[ew0 + lr];
  const int sN = src[pe];
  const int dN = dsts[ew0 + lr];
  const float iS = invn1[sN], iD = invn1[dN];
  const float2 f01 = *(const float2*)&ef[2 * pe];

  // ---- row pass: build message tile (coalesced rows, sd-only reduce) ----
  {
    const int k2 = lane * 2;
    const float wA0 = We1[k2],       wA1 = We1[k2 + 1];
    const float wB0 = We1[128 + k2], wB1 = We1[128 + k2 + 1];
    const float bE0 = be1[k2],       bE1 = be1[k2 + 1];
#pragma unroll 4
    for (int i = 0; i < 16; ++i) {
      const int s_i = __shfl(sN, i);
      const int d_i = __shfl(dN, i);
      bf2v hb = *(const bf2v*)&nfb[(size_t)s_i * 128 + k2];
      bf2v db = *(const bf2v*)&nfb[(size_t)d_i * 128 + k2];
      const float h0 = b2f(hb[0]), h1v = b2f(hb[1]);
      const float g0 = b2f(db[0]), g1 = b2f(db[1]);
      float sd = fmaf(h0, g0, h1v * g1);
#pragma unroll
      for (int o = 32; o >= 1; o >>= 1) sd += __shfl_xor(sd, o);
      const float c = sd * __shfl(iS, i) * __shfl(iD, i);
      const float f0 = __shfl(f01.x, i), f1 = __shfl(f01.y, i);
      const float w0 = fmaf(f0, wA0, fmaf(f1, wB0, bE0));
      const float w1 = fmaf(f0, wA1, fmaf(f1, wB1, bE1));
      bf2v pk;
      pk[0] = f2b(c * w0 * h0);
      pk[1] = f2b(c * w1 * h1v);
      *(bf2v*)&Uw[i * 136 + k2] = pk;
    }
  }
  FENCE();

  f4 acc[8];
#pragma unroll
  for (int a = 0; a < 8; ++a) acc[a] = (f4)0.f;

  // ---- stage 1: K = 128, outputs 128 (8 a-tiles) ----
#pragma unroll
  for (int kc = 0; kc < 128; kc += 32) {
    bf8 bF = *(const bf8*)&Uw[lr * 136 + kc + lq * 8];
    bf8 aF[8];
#pragma unroll
    for (int a = 0; a < 8; ++a)
      aF[a] = *(const bf8*)&WaT[(size_t)(a * 16 + lr) * 128 + kc + lq * 8];
#pragma unroll
    for (int a = 0; a < 8; ++a)
      acc[a] = __builtin_amdgcn_mfma_f32_16x16x32_bf16(aF[a], bF, acc[a], 0, 0, 0);
  }
  FENCE();

  // T in place (bf16)
#pragma unroll
  for (int a = 0; a < 8; ++a) {
    const int n = a * 16 + lq * 4;
    f4 bb = *(const f4*)&ba[n];
    bf4v pk;
#pragma unroll
    for (int r = 0; r < 4; ++r) pk[r] = f2b(fmaxf(acc[a][r] + bb[r], 0.f));
    *(bf4v*)&Uw[lr * 136 + n] = pk;
  }
  FENCE();

  // ---- stage 2 ----
#pragma unroll
  for (int a = 0; a < 8; ++a) acc[a] = (f4)0.f;
#pragma unroll
  for (int kc = 0; kc < 128; kc += 32) {
    bf8 bF = *(const bf8*)&Uw[lr * 136 + kc + lq * 8];
    bf8 aF[8];
#pragma unroll
    for (int a = 0; a < 8; ++a)
      aF[a] = *(const bf8*)&WbT[(size_t)(a * 16 + lr) * 128 + kc + lq * 8];
#pragma unroll
    for (int a = 0; a < 8; ++a)
      acc[a] = __builtin_amdgcn_mfma_f32_16x16x32_bf16(aF[a], bF, acc[a], 0, 0, 0);
  }
  FENCE();

  // R in place (bf16; run sums accumulate fp32)
#pragma unroll
  for (int a = 0; a < 8; ++a) {
    const int n = a * 16 + lq * 4;
    f4 bb = *(const f4*)&bbv[n];
    bf4v pk;
#pragma unroll
    for (int r = 0; r < 4; ++r) pk[r] = f2b(fmaxf(acc[a][r] + bb[r], 0.f));
    *(bf4v*)&Uw[lr * 136 + n] = pk;
  }
  FENCE();

  // seg-reduce over this wave's 16 sorted edges (lane owns 2 features)
  {
    const int f2i = lane * 2;
    float r0 = 0.f, r1 = 0.f;
    int pd = __shfl(dN, 0);
#pragma unroll 4
    for (int e = 0; e < 16; ++e) {
      const int d_e = __shfl(dN, e);   // wave-uniform
      if (d_e != pd) {
        atomicAdd(&s1[(size_t)pd * 128 + f2i], r0);
        atomicAdd(&s1[(size_t)pd * 128 + f2i + 1], r1);
        r0 = r1 = 0.f;
        pd = d_e;
      }
      bf2v v = *(const bf2v*)&Uw[e * 136 + f2i];
      r0 += b2f(v[0]);
      r1 += b2f(v[1]);
    }
    atomicAdd(&s1[(size_t)pd * 128 + f2i], r0);
    atomicAdd(&s1[(size_t)pd * 128 + f2i + 1], r1);
  }
}

// ---------------- edge-MLP layer 2: wave-private, barrier-free ----------------
// Each wave owns 16 edges; slab 16x264 bf16 (w1/Hs/m2/t2/r2 in place).

__global__ __launch_bounds__(256, 4) void edge_mlp2(
    const short* __restrict__ h1b, const float* __restrict__ ef,
    const int* __restrict__ src, const int* __restrict__ perm,
    const int* __restrict__ dsts, const float* __restrict__ invn2,
    const float* __restrict__ We1, const float* __restrict__ be1,
    const short* __restrict__ We2T, const float* __restrict__ be2,
    const short* __restrict__ WaT, const float* __restrict__ ba,
    const short* __restrict__ WbT, const float* __restrict__ bbv,
    float* __restrict__ s2)
{
  __shared__ __align__(16) short U[4 * 16 * 264];   // 33792 B, 8448 B/wave
  const int t = threadIdx.x;
  const int lane = t & 63, wv = t >> 6;
  const int lr = lane & 15, lq = lane >> 4;
  short* Uw = U + wv * (16 * 264);
  const int ew0 = blockIdx.x * 64 + wv * 16;

  const int pe = perm[ew0 + lr];
  const int sN = src[pe];
  const int dN = dsts[ew0 + lr];
  const float iS = invn2[sN], iD = invn2[dN];
  const float2 f01 = *(const float2*)&ef[2 * pe];

  // ---- build relu(w1) tile into Uw (k 0..127) ----
  {
    const int e = lane >> 2;
    const int kb = (lane & 3) * 32;
    const float f0 = __shfl(f01.x, e);
    const float f1 = __shfl(f01.y, e);
#pragma unroll
    for (int j = 0; j < 4; ++j) {
      const int k = kb + j * 8;
      f4 wa0 = *(const f4*)&We1[k];
      f4 wa1 = *(const f4*)&We1[k + 4];
      f4 wb0 = *(const f4*)&We1[128 + k];
      f4 wb1 = *(const f4*)&We1[128 + k + 4];
      f4 b0 = *(const f4*)&be1[k];
      f4 b1 = *(const f4*)&be1[k + 4];
      bf8 pk;
#pragma unroll
      for (int x = 0; x < 4; ++x) {
        pk[x]     = f2b(fmaxf(fmaf(f0, wa0[x], fmaf(f1, wb0[x], b0[x])), 0.f));
        pk[x + 4] = f2b(fmaxf(fmaf(f0, wa1[x], fmaf(f1, wb1[x], b1[x])), 0.f));
      }
      *(bf8*)&Uw[e * 264 + k] = pk;
    }
  }
  FENCE();

  f4 acc[16];
#pragma unroll
  for (int a = 0; a < 16; ++a) acc[a] = (f4)0.f;

  // ---- stage B: K = 128, outputs 256 (16 a-tiles, two halves of 8) ----
#pragma unroll
  for (int kc = 0; kc < 128; kc += 32) {
    bf8 bF = *(const bf8*)&Uw[lr * 264 + kc + lq * 8];
#pragma unroll
    for (int h = 0; h < 2; ++h) {
      bf8 aF[8];
#pragma unroll
      for (int a = 0; a < 8; ++a)
        aF[a] = *(const bf8*)&We2T[(size_t)((h * 8 + a) * 16 + lr) * 128 + kc + lq * 8];
#pragma unroll
      for (int a = 0; a < 8; ++a)
        acc[h * 8 + a] = __builtin_amdgcn_mfma_f32_16x16x32_bf16(aF[a], bF, acc[h * 8 + a], 0, 0, 0);
    }
  }
  FENCE();

  // ---- row pass: cos2 + stage hs rows into Uw (overwrites w1, now dead) ----
  float c_mine = 0.f;
  {
    const int k4 = lane * 4;
#pragma unroll 4
    for (int i = 0; i < 16; ++i) {
      const int s_i = __shfl(sN, i);
      const int d_i = __shfl(dN, i);
      bf4v hsb = *(const bf4v*)&h1b[(size_t)s_i * 256 + k4];  // 64x8B coalesced
      bf4v hdb = *(const bf4v*)&h1b[(size_t)d_i * 256 + k4];
      f4 hs = b2f4(hsb), hd = b2f4(hdb);
      float sd = 0.f;
#pragma unroll
      for (int r = 0; r < 4; ++r) sd = fmaf(hs[r], hd[r], sd);
#pragma unroll
      for (int o = 32; o >= 1; o >>= 1) sd += __shfl_xor(sd, o);
      const float c = sd * __shfl(iS, i) * __shfl(iD, i);
      if (lr == i) c_mine = c;
      *(bf4v*)&Uw[i * 264 + k4] = hsb;   // raw bf16 copy, no conversion
    }
  }
  FENCE();

  // ---- m2 = (w2 + be2) * cos * hs, in place over Hs ----
#pragma unroll
  for (int a = 0; a < 16; ++a) {
    const int n = a * 16 + lq * 4;
    f4 bb = *(const f4*)&be2[n];
    f4 hv = b2f4(*(const bf4v*)&Uw[lr * 264 + n]);
    bf4v pk;
#pragma unroll
    for (int r = 0; r < 4; ++r)
      pk[r] = f2b((acc[a][r] + bb[r]) * c_mine * hv[r]);
    *(bf4v*)&Uw[lr * 264 + n] = pk;
  }
  FENCE();

  // ---- stage C: K = 256, relu ----
#pragma unroll
  for (int a = 0; a < 16; ++a) acc[a] = (f4)0.f;
  for (int kc = 0; kc < 256; kc += 32) {
    bf8 bF = *(const bf8*)&Uw[lr * 264 + kc + lq * 8];
#pragma unroll
    for (int h = 0; h < 2; ++h) {
      bf8 aF[8];
#pragma unroll
      for (int a = 0; a < 8; ++a)
        aF[a] = *(const bf8*)&WaT[(size_t)((h * 8 + a) * 16 + lr) * 256 + kc + lq * 8];
#pragma unroll
      for (int a = 0; a < 8; ++a)
        acc[h * 8 + a] = __builtin_amdgcn_mfma_f32_16x16x32_bf16(aF[a], bF, acc[h * 8 + a], 0, 0, 0);
    }
  }
  FENCE();

  // t2 in place (bf16)
#pragma unroll
  for (int a = 0; a < 16; ++a) {
    const int n = a * 16 + lq * 4;
    f4 bb = *(const f4*)&ba[n];
    bf4v pk;
#pragma unroll
    for (int r = 0; r < 4; ++r) pk[r] = f2b(fmaxf(acc[a][r] + bb[r], 0.f));
    *(bf4v*)&Uw[lr * 264 + n] = pk;
  }
  FENCE();

  // ---- stage D: K = 256 ----
#pragma unroll
  for (int a = 0; a < 16; ++a) acc[a] = (f4)0.f;
  for (int kc = 0; kc < 256; kc += 32) {
    bf8 bF = *(const bf8*)&Uw[lr * 264 + kc + lq * 8];
#pragma unroll
    for (int h = 0; h < 2; ++h) {
      bf8 aF[8];
#pragma unroll
      for (int a = 0; a < 8; ++a)
        aF[a] = *(const bf8*)&WbT[(size_t)((h * 8 + a) * 16 + lr) * 256 + kc + lq * 8];
#pragma unroll
      for (int a = 0; a < 8; ++a)
        acc[h * 8 + a] = __builtin_amdgcn_mfma_f32_16x16x32_bf16(aF[a], bF, acc[h * 8 + a], 0, 0, 0);
    }
  }
  FENCE();

  // r2 in place (bf16; run sums accumulate fp32)
#pragma unroll
  for (int a = 0; a < 16; ++a) {
    const int n = a * 16 + lq * 4;
    f4 bb = *(const f4*)&bbv[n];
    bf4v pk;
#pragma unroll
    for (int r = 0; r < 4; ++r) pk[r] = f2b(fmaxf(acc[a][r] + bb[r], 0.f));
    *(bf4v*)&Uw[lr * 264 + n] = pk;
  }
  FENCE();

  // seg-reduce over this wave's 16 sorted edges (lane owns 4 features)
  {
    const int f4i = lane * 4;
    f4 run = (f4)0.f;
    int pd = __shfl(dN, 0);
#pragma unroll 4
    for (int e = 0; e < 16; ++e) {
      const int d_e = __shfl(dN, e);   // wave-uniform
      if (d_e != pd) {
        float* o = &s2[(size_t)pd * 256 + f4i];
        atomicAdd(&o[0], run[0]); atomicAdd(&o[1], run[1]);
        atomicAdd(&o[2], run[2]); atomicAdd(&o[3], run[3]);
        run = (f4)0.f;
        pd = d_e;
      }
      f4 v = b2f4(*(const bf4v*)&Uw[e * 264 + f4i]);
      run += v;
    }
    float* o = &s2[(size_t)pd * 256 + f4i];
    atomicAdd(&o[0], run[0]); atomicAdd(&o[1], run[1]);
    atomicAdd(&o[2], run[2]); atomicAdd(&o[3], run[3]);
  }
}

// ---------------- node linear 1 (bf16 MFMA) -> h1b (bf16) ---------------------

__global__ __launch_bounds__(256, 3) void h1m_k(
    const float* __restrict__ nf, const float* __restrict__ s1,
    const int* __restrict__ cnt, const short* __restrict__ Wl1T,
    const float* __restrict__ bl1, short* __restrict__ h1b)
{
  __shared__ __align__(16) short As[64 * 264];
  const int t = threadIdx.x;
  const int v0 = blockIdx.x * 64;

  {
    const int row = t >> 2;
    const int kb = (t & 3) * 64;
    int gn = v0 + row;
    if (gn >= NN) gn = NN - 1;
    const float inv = 1.f / fmaxf((float)cnt[gn], 1.f);
#pragma unroll
    for (int j = 0; j < 64; j += 8) {
      const int k = kb + j;
      f4 x0, x1;
      if (k < 128) {
        x0 = *(const f4*)&nf[(size_t)gn * 128 + k];
        x1 = *(const f4*)&nf[(size_t)gn * 128 + k + 4];
      } else {
        x0 = *(const f4*)&s1[(size_t)gn * 128 + (k - 128)];
        x1 = *(const f4*)&s1[(size_t)gn * 128 + (k - 124)];
#pragma unroll
        for (int x = 0; x < 4; ++x) { x0[x] *= inv; x1[x] *= inv; }
      }
      bf8 pk;
#pragma unroll
      for (int x = 0; x < 4; ++x) { pk[x] = f2b(x0[x]); pk[x + 4] = f2b(x1[x]); }
      *(bf8*)&As[row * 264 + k] = pk;
    }
  }
  __syncthreads();

  const int lane = t & 63, wv = t >> 6;
  const int lr = lane & 15;
  const int lq = lane >> 4;
  const int n0 = wv * 64;

  f4 acc[4][4];
#pragma unroll
  for (int a = 0; a < 4; ++a)
#pragma unroll
    for (int b = 0; b < 4; ++b) acc[a][b] = (f4)0.f;

  for (int kc = 0; kc < 256; kc += 32) {
    bf8 aF[4], bF[4];
#pragma unroll
    for (int a = 0; a < 4; ++a)
      aF[a] = *(const bf8*)&Wl1T[(size_t)(n0 + a * 16 + lr) * 256 + kc + lq * 8];
#pragma unroll
    for (int b = 0; b < 4; ++b)
      bF[b] = *(const bf8*)&As[(b * 16 + lr) * 264 + kc + lq * 8];
#pragma unroll
    for (int a = 0; a < 4; ++a)
#pragma unroll
      for (int b = 0; b < 4; ++b)
        acc[a][b] = __builtin_amdgcn_mfma_f32_16x16x32_bf16(aF[a], bF[b], acc[a][b], 0, 0, 0);
  }

#pragma unroll
  for (int b = 0; b < 4; ++b) {
    const int gn = v0 + b * 16 + lr;
    if (gn >= NN) continue;
#pragma unroll
    for (int a = 0; a < 4; ++a) {
      const int n = n0 + a * 16 + lq * 4;
      f4 bb = *(const f4*)&bl1[n];
      bf4v pk;
      pk[0] = f2b(fmaxf(acc[a][b][0] + bb[0], 0.f));
      pk[1] = f2b(fmaxf(acc[a][b][1] + bb[1], 0.f));
      pk[2] = f2b(fmaxf(acc[a][b][2] + bb[2], 0.f));
      pk[3] = f2b(fmaxf(acc[a][b][3] + bb[3], 0.f));
      *(bf4v*)&h1b[(size_t)gn * 256 + n] = pk;
    }
  }
}

// ---------------- final linear: out = concat(h1b, s2/cnt) @ Wl2 + bl2 ---------

__global__ __launch_bounds__(256) void out_k(
    const short* __restrict__ h1b, const float* __restrict__ s2,
    const int* __restrict__ cnt, const float* __restrict__ Wl2,
    const float* __restrict__ bl2, float* __restrict__ out)
{
  __shared__ float A8[8][512];
  const int n0 = blockIdx.x * 8;
  const int tx = threadIdx.x;
  const int ty = threadIdx.y;
  const int t = ty * 32 + tx;
  const int row = t >> 5;
  const int k0 = (t & 31) * 16;
  const int n = n0 + row;
  const float inv = 1.0f / fmaxf((float)cnt[n], 1.0f);
#pragma unroll
  for (int i = 0; i < 16; i += 4) {
    int k = k0 + i;
    f4 v;
    if (k < 256) {
      v = b2f4(*(const bf4v*)&h1b[(size_t)n * 256 + k]);
    } else {
      v = *(const f4*)&s2[(size_t)n * 256 + (k - 256)];
      v[0] *= inv; v[1] *= inv; v[2] *= inv; v[3] *= inv;
    }
    *(f4*)&A8[row][k] = v;
  }
  __syncthreads();
  float acc = bl2[tx];
#pragma unroll 8
  for (int k = 0; k < 512; k++) acc = fmaf(A8[ty][k], Wl2[(size_t)k * 32 + tx], acc);
  out[(size_t)(n0 + ty) * 32 + tx] = acc;
}

// ---------------- launch ------------------------------------------------------

extern "C" void kernel_launch(void* const* d_in, const int* in_sizes, int n_in,
                              void* d_out, int out_size, void* d_ws, size_t ws_size,
                              hipStream_t stream) {
  const float* nf   = (const float*)d_in[0];
  const float* ef   = (const float*)d_in[1];
  const int*   src  = (const int*)d_in[2];
  const int*   dst  = (const int*)d_in[3];
  const float* We1  = (const float*)d_in[4];
  const float* be1  = (const float*)d_in[5];
  const float* Wr1a = (const float*)d_in[6];
  const float* br1a = (const float*)d_in[7];
  const float* Wr1b = (const float*)d_in[8];
  const float* br1b = (const float*)d_in[9];
  const float* Wl1  = (const float*)d_in[10];
  const float* bl1  = (const float*)d_in[11];
  const float* We2  = (const float*)d_in[12];
  const float* be2  = (const float*)d_in[13];
  const float* Wr2a = (const float*)d_in[14];
  const float* br2a = (const float*)d_in[15];
  const float* Wr2b = (const float*)d_in[16];
  const float* br2b = (const float*)d_in[17];
  const float* Wl2  = (const float*)d_in[18];
  const float* bl2  = (const float*)d_in[19];

  float* ws = (float*)d_ws;
  float* s1   = ws;                             // N*128 f
  float* s2   = s1 + (size_t)NN * 128;          // N*256 f
  int*   cnt  = (int*)(s2 + (size_t)NN * 256);  // N
  short* h1b  = (short*)(cnt + NN);             // N*256 bf16
  short* nfb  = h1b + (size_t)NN * 256;         // N*128 bf16
  short* WaT1 = nfb + (size_t)NN * 128;         // 128*128 bf16
  short* WbT1 = WaT1 + 128 * 128;               // 128*128
  short* We2T = WbT1 + 128 * 128;               // 256*128
  short* WaT2 = We2T + 256 * 128;               // 256*256
  short* WbT2 = WaT2 + 256 * 256;               // 256*256
  short* Wl1T = WbT2 + 256 * 256;               // 256*256
  int*   off2 = (int*)(Wl1T + 256 * 256);       // N
  int*   perm = off2 + NN;                      // E
  int*   dsts = perm + NE;                      // E
  float* invn1 = (float*)(dsts + NE);           // N
  float* invn2 = invn1 + NN;                    // N

  size_t need = ((size_t)NN * 128 + (size_t)NN * 256 + NN) * 4 +
                ((size_t)NN * 256 + (size_t)NN * 128 +
                 (size_t)128 * 128 * 2 + (size_t)256 * 128 +
                 (size_t)256 * 256 * 3) * 2 +
                ((size_t)NN + 2 * (size_t)NE + 2 * (size_t)NN) * 4;
  if (ws_size < need) return;

  // weight transpose+convert and nf convert (tiny)
  wt_k<<<(128 * 128 + 255) / 256, 256, 0, stream>>>(Wr1a, WaT1, 128, 128);
  wt_k<<<(128 * 128 + 255) / 256, 256, 0, stream>>>(Wr1b, WbT1, 128, 128);
  wt_k<<<(128 * 256 + 255) / 256, 256, 0, stream>>>(We2, We2T, 128, 256);
  wt_k<<<(256 * 256 + 255) / 256, 256, 0, stream>>>(Wr2a, WaT2, 256, 256);
  wt_k<<<(256 * 256 + 255) / 256, 256, 0, stream>>>(Wr2b, WbT2, 256, 256);
  wt_k<<<(256 * 256 + 255) / 256, 256, 0, stream>>>(Wl1, Wl1T, 256, 256);
  cvt_k<<<(NN * 128 / 4 + 255) / 256, 256, 0, stream>>>(nf, nfb, NN * 128 / 4);
  norm1_k<<<(NN + 3) / 4, 256, 0, stream>>>(nfb, invn1);

  // zero s1, s2, cnt (contiguous)
  hipMemsetAsync(s1, 0, ((size_t)NN * 128 + (size_t)NN * 256 + NN) * 4, stream);

  cnt_k<<<NE / 256, 256, 0, stream>>>(dst, cnt);

  // counting sort by dst
  scan_k<<<1, 1024, 0, stream>>>(cnt, off2);
  perm_k<<<NE / 256, 256, 0, stream>>>(dst, off2, perm, dsts);

  edge_mlp1<<<NE / 64, 256, 0, stream>>>(nfb, ef, src, perm, dsts, invn1,
                                         We1, be1, WaT1, br1a, WbT1, br1b, s1);

  h1m_k<<<(NN + 63) / 64, 256, 0, stream>>>(nf, s1, cnt, Wl1T, bl1, h1b);
  norm2_k<<<(NN + 3) / 4, 256, 0, stream>>>(h1b, invn2);

  edge_mlp2<<<NE / 64, 256, 0, stream>>>(h1b, ef, src, perm, dsts, invn2,
                                         We1, be1, We2T, be2, WaT2, br2a,
                                         WbT2, br2b, s2);

  out_k<<<NN / 8, dim3(32, 8), 0, stream>>>(h1b, s2, cnt, Wl2, bl2, (float*)d_out);
}

// Round 12
// 1336.266 us; speedup vs baseline: 2.2987x; 2.2987x over previous
//
#include <hip/hip_runtime.h>
#include <math.h>

#define NN 50000
#define NE 800000

typedef short bf8 __attribute__((ext_vector_type(8)));
typedef short bf4v __attribute__((ext_vector_type(4)));
typedef short bf2v __attribute__((ext_vector_type(2)));
typedef float f4 __attribute__((ext_vector_type(4)));

// float -> bf16 bits, round-to-nearest-even (values are finite)
__device__ __forceinline__ short f2b(float f) {
  unsigned int u = __float_as_uint(f);
  unsigned int r = (u + 0x7FFFu + ((u >> 16) & 1u)) >> 16;
  return (short)(unsigned short)r;
}
__device__ __forceinline__ float b2f(short s) {
  return __uint_as_float(((unsigned int)(unsigned short)s) << 16);
}
__device__ __forceinline__ f4 b2f4(bf4v p) {
  f4 v;
  v[0] = b2f(p[0]); v[1] = b2f(p[1]); v[2] = b2f(p[2]); v[3] = b2f(p[3]);
  return v;
}

// ---------------- weight transpose + bf16 convert -----------------------------
__global__ __launch_bounds__(256) void wt_k(const float* __restrict__ in,
                                            short* __restrict__ out,
                                            int K, int N) {
  int i = blockIdx.x * 256 + threadIdx.x;
  if (i >= K * N) return;
  int n = i / K, k = i - n * K;
  out[i] = f2b(in[(size_t)k * N + n]);
}

__global__ __launch_bounds__(256) void cvt_k(const float* __restrict__ in,
                                             short* __restrict__ out, int n4) {
  int i = blockIdx.x * 256 + threadIdx.x;
  if (i >= n4) return;
  f4 v = *(const f4*)&in[(size_t)i * 4];
  bf4v p;
  p[0] = f2b(v[0]); p[1] = f2b(v[1]); p[2] = f2b(v[2]); p[3] = f2b(v[3]);
  *(bf4v*)&out[(size_t)i * 4] = p;
}

// ---------------- per-node inverse norms --------------------------------------
__global__ __launch_bounds__(256) void norm1_k(const short* __restrict__ nfb,
                                               float* __restrict__ invn) {
  const int node = blockIdx.x * 4 + (threadIdx.x >> 6);
  if (node >= NN) return;
  const int lane = threadIdx.x & 63;
  bf2v hb = *(const bf2v*)&nfb[(size_t)node * 128 + lane * 2];
  float h0 = b2f(hb[0]), h1v = b2f(hb[1]);
  float ss = fmaf(h0, h0, h1v * h1v);
#pragma unroll
  for (int o = 32; o >= 1; o >>= 1) ss += __shfl_xor(ss, o);
  if (lane == 0) invn[node] = 1.f / fmaxf(sqrtf(ss), 1e-12f);
}

__global__ __launch_bounds__(256) void norm2_k(const short* __restrict__ h1b,
                                               float* __restrict__ invn) {
  const int node = blockIdx.x * 4 + (threadIdx.x >> 6);
  if (node >= NN) return;
  const int lane = threadIdx.x & 63;
  f4 h = b2f4(*(const bf4v*)&h1b[(size_t)node * 256 + lane * 4]);
  float ss = 0.f;
#pragma unroll
  for (int r = 0; r < 4; ++r) ss = fmaf(h[r], h[r], ss);
#pragma unroll
  for (int o = 32; o >= 1; o >>= 1) ss += __shfl_xor(ss, o);
  if (lane == 0) invn[node] = 1.f / fmaxf(sqrtf(ss), 1e-12f);
}

// ---------------- degree count -------------------------------------------------
__global__ __launch_bounds__(256) void cnt_k(const int* __restrict__ dst,
                                             int* __restrict__ cnt) {
  int e = blockIdx.x * 256 + threadIdx.x;
  if (e >= NE) return;
  atomicAdd(&cnt[dst[e]], 1);
}

// ---------------- counting-sort by dst ----------------------------------------
__global__ __launch_bounds__(1024) void scan_k(const int* __restrict__ cnt,
                                               int* __restrict__ off2) {
  __shared__ int buf[1024];
  __shared__ int carry_s;
  const int t = threadIdx.x;
  if (t == 0) carry_s = 0;
  __syncthreads();
  const int nch = (NN + 1023) / 1024;
  for (int ch = 0; ch < nch; ++ch) {
    const int i = ch * 1024 + t;
    const int v = (i < NN) ? cnt[i] : 0;
    buf[t] = v;
    __syncthreads();
#pragma unroll
    for (int o = 1; o < 1024; o <<= 1) {
      int x = (t >= o) ? buf[t - o] : 0;
      __syncthreads();
      buf[t] += x;
      __syncthreads();
    }
    const int incl = buf[t];
    const int carry = carry_s;
    if (i < NN) off2[i] = carry + incl - v;
    __syncthreads();
    if (t == 1023) carry_s = carry + incl;
    __syncthreads();
  }
}

__global__ __launch_bounds__(256) void perm_k(const int* __restrict__ dst,
                                              int* __restrict__ off2,
                                              int* __restrict__ perm,
                                              int* __restrict__ dsts) {
  int e = blockIdx.x * 256 + threadIdx.x;
  if (e >= NE) return;
  int d = dst[e];
  int p = atomicAdd(&off2[d], 1);
  perm[p] = e;
  dsts[p] = d;
}

// ---------------- fused edge-MLP layer 1 (bf16 MFMA, sd-only row pass) --------

__global__ __launch_bounds__(256, 5) void edge_mlp1(
    const short* __restrict__ nfb, const float* __restrict__ ef,
    const int* __restrict__ src, const int* __restrict__ perm,
    const int* __restrict__ dsts, const float* __restrict__ invn1,
    const float* __restrict__ We1, const float* __restrict__ be1,
    const short* __restrict__ WaT, const float* __restrict__ ba,
    const short* __restrict__ WbT, const float* __restrict__ bbv,
    float* __restrict__ s1)
{
  __shared__ __align__(16) short Ms[64 * 136];   // 17408 B (M / T / R reuse)
  __shared__ int dse[64];
  __shared__ int pes[64];
  __shared__ int sse[64];
  const int t = threadIdx.x;
  const int e0 = blockIdx.x * 64;
  const int lane = t & 63, wv = t >> 6;

  if (t < 64) {
    const int pe = perm[e0 + t];
    pes[t] = pe;
    dse[t] = dsts[e0 + t];
    sse[t] = src[pe];
  }
  __syncthreads();

  // ---- row pass: 16 edges/wave; coalesced rows, sd-only wave-reduce ----
  {
    const int k2 = lane * 2;
    const float wA0 = We1[k2],       wA1 = We1[k2 + 1];
    const float wB0 = We1[128 + k2], wB1 = We1[128 + k2 + 1];
    const float bE0 = be1[k2],       bE1 = be1[k2 + 1];
#pragma unroll 4
    for (int i = 0; i < 16; ++i) {
      const int e = wv * 16 + i;
      const int s = sse[e];
      const int d = dse[e];
      bf2v hb = *(const bf2v*)&nfb[(size_t)s * 128 + k2];   // 64x4B coalesced
      bf2v db = *(const bf2v*)&nfb[(size_t)d * 128 + k2];
      const float h0 = b2f(hb[0]), h1v = b2f(hb[1]);
      const float g0 = b2f(db[0]), g1 = b2f(db[1]);
      float sd = fmaf(h0, g0, h1v * g1);
#pragma unroll
      for (int o = 32; o >= 1; o >>= 1) sd += __shfl_xor(sd, o);
      const float c = sd * invn1[s] * invn1[d];
      const float2 f01 = *(const float2*)&ef[2 * pes[e]];   // uniform broadcast
      const float w0 = fmaf(f01.x, wA0, fmaf(f01.y, wB0, bE0));
      const float w1 = fmaf(f01.x, wA1, fmaf(f01.y, wB1, bE1));
      bf2v pk;
      pk[0] = f2b(c * w0 * h0);
      pk[1] = f2b(c * w1 * h1v);
      *(bf2v*)&Ms[e * 136 + k2] = pk;
    }
  }
  __syncthreads();

  const int lr = lane & 15;
  const int lq = lane >> 4;
  const int n0 = wv * 32;

  f4 acc[2][4];
#pragma unroll
  for (int a = 0; a < 2; ++a)
#pragma unroll
    for (int b = 0; b < 4; ++b) acc[a][b] = (f4)0.f;

  // ---- stage 1: K = 128 ----
#pragma unroll
  for (int kc = 0; kc < 128; kc += 32) {
    bf8 aF[2], bF[4];
#pragma unroll
    for (int a = 0; a < 2; ++a)
      aF[a] = *(const bf8*)&WaT[(size_t)(n0 + a * 16 + lr) * 128 + kc + lq * 8];
#pragma unroll
    for (int b = 0; b < 4; ++b)
      bF[b] = *(const bf8*)&Ms[(b * 16 + lr) * 136 + kc + lq * 8];
#pragma unroll
    for (int a = 0; a < 2; ++a)
#pragma unroll
      for (int b = 0; b < 4; ++b)
        acc[a][b] = __builtin_amdgcn_mfma_f32_16x16x32_bf16(aF[a], bF[b], acc[a][b], 0, 0, 0);
  }
  __syncthreads();

  // T[e][n] = relu(acc + ba[n]) -> Ms
#pragma unroll
  for (int a = 0; a < 2; ++a) {
    const int n = n0 + a * 16 + lq * 4;
    f4 bb = *(const f4*)&ba[n];
#pragma unroll
    for (int b = 0; b < 4; ++b) {
      bf4v pk;
#pragma unroll
      for (int r = 0; r < 4; ++r) pk[r] = f2b(fmaxf(acc[a][b][r] + bb[r], 0.f));
      *(bf4v*)&Ms[(b * 16 + lr) * 136 + n] = pk;
    }
  }
  __syncthreads();

  // ---- stage 2: K = 128 ----
#pragma unroll
  for (int a = 0; a < 2; ++a)
#pragma unroll
    for (int b = 0; b < 4; ++b) acc[a][b] = (f4)0.f;
#pragma unroll
  for (int kc = 0; kc < 128; kc += 32) {
    bf8 aF[2], bF[4];
#pragma unroll
    for (int a = 0; a < 2; ++a)
      aF[a] = *(const bf8*)&WbT[(size_t)(n0 + a * 16 + lr) * 128 + kc + lq * 8];
#pragma unroll
    for (int b = 0; b < 4; ++b)
      bF[b] = *(const bf8*)&Ms[(b * 16 + lr) * 136 + kc + lq * 8];
#pragma unroll
    for (int a = 0; a < 2; ++a)
#pragma unroll
      for (int b = 0; b < 4; ++b)
        acc[a][b] = __builtin_amdgcn_mfma_f32_16x16x32_bf16(aF[a], bF[b], acc[a][b], 0, 0, 0);
  }
  __syncthreads();   // all waves done reading Ms before R overwrite

  // R[e][n] = relu(acc + bb[n]) -> Ms (bf16; sums still accumulate in fp32)
#pragma unroll
  for (int a = 0; a < 2; ++a) {
    const int n = n0 + a * 16 + lq * 4;
    f4 bb = *(const f4*)&bbv[n];
#pragma unroll
    for (int b = 0; b < 4; ++b) {
      bf4v pk;
#pragma unroll
      for (int r = 0; r < 4; ++r) pk[r] = f2b(fmaxf(acc[a][b][r] + bb[r], 0.f));
      *(bf4v*)&Ms[(b * 16 + lr) * 136 + n] = pk;
    }
  }
  __syncthreads();

  // segmented reduce over sorted dst
  {
    const int f = t & 127;
    const int eb = (t >> 7) * 32;
    float run = 0.f;
    int pd = dse[eb];
#pragma unroll 4
    for (int e = eb; e < eb + 32; ++e) {
      const int d = dse[e];          // wave-uniform
      if (d != pd) {
        atomicAdd(&s1[(size_t)pd * 128 + f], run);
        run = 0.f;
        pd = d;
      }
      run += b2f(Ms[e * 136 + f]);
    }
    atomicAdd(&s1[(size_t)pd * 128 + f], run);
  }
}

// ---------------- fused edge-MLP layer 2 (bf16 MFMA, sd-only row pass) --------
// LDS union: Ws (17408 B) lives inside M2s (33792 B). ~34.5 KB -> 4 blocks/CU.
// Epilogue: r2 staged bf16 in M2s, single seg-reduce (1 barrier, not 4).

__global__ __launch_bounds__(256, 4) void edge_mlp2(
    const short* __restrict__ h1b, const float* __restrict__ ef,
    const int* __restrict__ src, const int* __restrict__ perm,
    const int* __restrict__ dsts, const float* __restrict__ invn2,
    const float* __restrict__ We1, const float* __restrict__ be1,
    const short* __restrict__ We2T, const float* __restrict__ be2,
    const short* __restrict__ WaT, const float* __restrict__ ba,
    const short* __restrict__ WbT, const float* __restrict__ bbv,
    float* __restrict__ s2)
{
  __shared__ __align__(16) short U[64 * 264];    // 33792 B: Ws then M2s
  __shared__ int dse[64];
  __shared__ int pes[64];
  __shared__ int sse[64];
  short* Ws  = U;                                // 64 x 136
  short* M2s = U;                                // 64 x 264
  const int t = threadIdx.x;
  const int e0 = blockIdx.x * 64;
  const int lane = t & 63, wv = t >> 6;
  const int lr = lane & 15;
  const int lq = lane >> 4;
  const int n0 = wv * 64;

  if (t < 64) {
    const int pe = perm[e0 + t];
    pes[t] = pe;
    dse[t] = dsts[e0 + t];
    sse[t] = src[pe];
  }
  __syncthreads();

  // ---- build relu(w1) tile (bf16) into Ws ----
  {
    const int e = t >> 2;
    const int kb = (t & 3) * 32;
    const int pe = pes[e];
    const float f0 = ef[2 * pe], f1 = ef[2 * pe + 1];
#pragma unroll
    for (int j = 0; j < 4; ++j) {
      const int k = kb + j * 8;
      f4 wa0 = *(const f4*)&We1[k];
      f4 wa1 = *(const f4*)&We1[k + 4];
      f4 wb0 = *(const f4*)&We1[128 + k];
      f4 wb1 = *(const f4*)&We1[128 + k + 4];
      f4 b0 = *(const f4*)&be1[k];
      f4 b1 = *(const f4*)&be1[k + 4];
      bf8 pk;
#pragma unroll
      for (int x = 0; x < 4; ++x) {
        pk[x]     = f2b(fmaxf(fmaf(f0, wa0[x], fmaf(f1, wb0[x], b0[x])), 0.f));
        pk[x + 4] = f2b(fmaxf(fmaf(f0, wa1[x], fmaf(f1, wb1[x], b1[x])), 0.f));
      }
      *(bf8*)&Ws[e * 136 + k] = pk;
    }
  }
  __syncthreads();

  f4 acc[4][4];
#pragma unroll
  for (int a = 0; a < 4; ++a)
#pragma unroll
    for (int b = 0; b < 4; ++b) acc[a][b] = (f4)0.f;

  // ---- stage B: K = 128 (reads Ws) ----
#pragma unroll
  for (int kc = 0; kc < 128; kc += 32) {
    bf8 aF[4], bF[4];
#pragma unroll
    for (int a = 0; a < 4; ++a)
      aF[a] = *(const bf8*)&We2T[(size_t)(n0 + a * 16 + lr) * 128 + kc + lq * 8];
#pragma unroll
    for (int b = 0; b < 4; ++b)
      bF[b] = *(const bf8*)&Ws[(b * 16 + lr) * 136 + kc + lq * 8];
#pragma unroll
    for (int a = 0; a < 4; ++a)
#pragma unroll
      for (int b = 0; b < 4; ++b)
        acc[a][b] = __builtin_amdgcn_mfma_f32_16x16x32_bf16(aF[a], bF[b], acc[a][b], 0, 0, 0);
  }
  __syncthreads();   // Ws dead; M2s region may now be written

  // w2[e][n] = acc + be2[n] -> M2s (bf16, no cos/h yet)
#pragma unroll
  for (int b = 0; b < 4; ++b) {
#pragma unroll
    for (int a = 0; a < 4; ++a) {
      const int n = n0 + a * 16 + lq * 4;
      f4 bb = *(const f4*)&be2[n];
      bf4v pk;
#pragma unroll
      for (int r = 0; r < 4; ++r) pk[r] = f2b(acc[a][b][r] + bb[r]);
      *(bf4v*)&M2s[(b * 16 + lr) * 264 + n] = pk;
    }
  }
  __syncthreads();

  // ---- row pass: 16 edges/wave; coalesced rows, sd-only wave-reduce ----
  {
    const int k4 = lane * 4;
#pragma unroll 4
    for (int i = 0; i < 16; ++i) {
      const int e = wv * 16 + i;
      const int s = sse[e];
      const int d = dse[e];
      f4 hs = b2f4(*(const bf4v*)&h1b[(size_t)s * 256 + k4]);  // 64x8B coalesced
      f4 hd = b2f4(*(const bf4v*)&h1b[(size_t)d * 256 + k4]);
      float sd = 0.f;
#pragma unroll
      for (int r = 0; r < 4; ++r) sd = fmaf(hs[r], hd[r], sd);
#pragma unroll
      for (int o = 32; o >= 1; o >>= 1) sd += __shfl_xor(sd, o);
      const float c = sd * invn2[s] * invn2[d];
      f4 w = b2f4(*(const bf4v*)&M2s[e * 264 + k4]);
      bf4v pk;
#pragma unroll
      for (int r = 0; r < 4; ++r) pk[r] = f2b(w[r] * c * hs[r]);
      *(bf4v*)&M2s[e * 264 + k4] = pk;
    }
  }
  __syncthreads();

  // ---- stage C: K = 256, relu ----
#pragma unroll
  for (int a = 0; a < 4; ++a)
#pragma unroll
    for (int b = 0; b < 4; ++b) acc[a][b] = (f4)0.f;
  for (int kc = 0; kc < 256; kc += 32) {
    bf8 aF[4], bF[4];
#pragma unroll
    for (int a = 0; a < 4; ++a)
      aF[a] = *(const bf8*)&WaT[(size_t)(n0 + a * 16 + lr) * 256 + kc + lq * 8];
#pragma unroll
    for (int b = 0; b < 4; ++b)
      bF[b] = *(const bf8*)&M2s[(b * 16 + lr) * 264 + kc + lq * 8];
#pragma unroll
    for (int a = 0; a < 4; ++a)
#pragma unroll
      for (int b = 0; b < 4; ++b)
        acc[a][b] = __builtin_amdgcn_mfma_f32_16x16x32_bf16(aF[a], bF[b], acc[a][b], 0, 0, 0);
  }
  __syncthreads();

#pragma unroll
  for (int a = 0; a < 4; ++a) {
    const int n = n0 + a * 16 + lq * 4;
    f4 bb = *(const f4*)&ba[n];
#pragma unroll
    for (int b = 0; b < 4; ++b) {
      bf4v pk;
#pragma unroll
      for (int r = 0; r < 4; ++r) pk[r] = f2b(fmaxf(acc[a][b][r] + bb[r], 0.f));
      *(bf4v*)&M2s[(b * 16 + lr) * 264 + n] = pk;
    }
  }
  __syncthreads();

  // ---- stage D: K = 256 ----
#pragma unroll
  for (int a = 0; a < 4; ++a)
#pragma unroll
    for (int b = 0; b < 4; ++b) acc[a][b] = (f4)0.f;
  for (int kc = 0; kc < 256; kc += 32) {
    bf8 aF[4], bF[4];
#pragma unroll
    for (int a = 0; a < 4; ++a)
      aF[a] = *(const bf8*)&WbT[(size_t)(n0 + a * 16 + lr) * 256 + kc + lq * 8];
#pragma unroll
    for (int b = 0; b < 4; ++b)
      bF[b] = *(const bf8*)&M2s[(b * 16 + lr) * 264 + kc + lq * 8];
#pragma unroll
    for (int a = 0; a < 4; ++a)
#pragma unroll
      for (int b = 0; b < 4; ++b)
        acc[a][b] = __builtin_amdgcn_mfma_f32_16x16x32_bf16(aF[a], bF[b], acc[a][b], 0, 0, 0);
  }
  __syncthreads();  // all waves done reading M2s before r2 overwrite

  // r2[e][n] = relu(acc + bb[n]) -> M2s (bf16; run sums accumulate fp32)
#pragma unroll
  for (int a = 0; a < 4; ++a) {
    const int n = n0 + a * 16 + lq * 4;
    f4 bb = *(const f4*)&bbv[n];
#pragma unroll
    for (int b = 0; b < 4; ++b) {
      bf4v pk;
#pragma unroll
      for (int r = 0; r < 4; ++r) pk[r] = f2b(fmaxf(acc[a][b][r] + bb[r], 0.f));
      *(bf4v*)&M2s[(b * 16 + lr) * 264 + n] = pk;
    }
  }
  __syncthreads();

  // single seg-reduce: thread t owns feature t across the 64 sorted edges
  {
    const int f = t;               // 0..255
    float run = 0.f;
    int pd = dse[0];
#pragma unroll 4
    for (int e = 0; e < 64; ++e) {
      const int d = dse[e];        // wave-uniform
      if (d != pd) {
        atomicAdd(&s2[(size_t)pd * 256 + f], run);
        run = 0.f;
        pd = d;
      }
      run += b2f(M2s[e * 264 + f]);
    }
    atomicAdd(&s2[(size_t)pd * 256 + f], run);
  }
}

// ---------------- node linear 1 (bf16 MFMA) -> h1b (bf16) ---------------------

__global__ __launch_bounds__(256, 3) void h1m_k(
    const float* __restrict__ nf, const float* __restrict__ s1,
    const int* __restrict__ cnt, const short* __restrict__ Wl1T,
    const float* __restrict__ bl1, short* __restrict__ h1b)
{
  __shared__ __align__(16) short As[64 * 264];
  const int t = threadIdx.x;
  const int v0 = blockIdx.x * 64;

  {
    const int row = t >> 2;
    const int kb = (t & 3) * 64;
    int gn = v0 + row;
    if (gn >= NN) gn = NN - 1;
    const float inv = 1.f / fmaxf((float)cnt[gn], 1.f);
#pragma unroll
    for (int j = 0; j < 64; j += 8) {
      const int k = kb + j;
      f4 x0, x1;
      if (k < 128) {
        x0 = *(const f4*)&nf[(size_t)gn * 128 + k];
        x1 = *(const f4*)&nf[(size_t)gn * 128 + k + 4];
      } else {
        x0 = *(const f4*)&s1[(size_t)gn * 128 + (k - 128)];
        x1 = *(const f4*)&s1[(size_t)gn * 128 + (k - 124)];
#pragma unroll
        for (int x = 0; x < 4; ++x) { x0[x] *= inv; x1[x] *= inv; }
      }
      bf8 pk;
#pragma unroll
      for (int x = 0; x < 4; ++x) { pk[x] = f2b(x0[x]); pk[x + 4] = f2b(x1[x]); }
      *(bf8*)&As[row * 264 + k] = pk;
    }
  }
  __syncthreads();

  const int lane = t & 63, wv = t >> 6;
  const int lr = lane & 15;
  const int lq = lane >> 4;
  const int n0 = wv * 64;

  f4 acc[4][4];
#pragma unroll
  for (int a = 0; a < 4; ++a)
#pragma unroll
    for (int b = 0; b < 4; ++b) acc[a][b] = (f4)0.f;

  for (int kc = 0; kc < 256; kc += 32) {
    bf8 aF[4], bF[4];
#pragma unroll
    for (int a = 0; a < 4; ++a)
      aF[a] = *(const bf8*)&Wl1T[(size_t)(n0 + a * 16 + lr) * 256 + kc + lq * 8];
#pragma unroll
    for (int b = 0; b < 4; ++b)
      bF[b] = *(const bf8*)&As[(b * 16 + lr) * 264 + kc + lq * 8];
#pragma unroll
    for (int a = 0; a < 4; ++a)
#pragma unroll
      for (int b = 0; b < 4; ++b)
        acc[a][b] = __builtin_amdgcn_mfma_f32_16x16x32_bf16(aF[a], bF[b], acc[a][b], 0, 0, 0);
  }

#pragma unroll
  for (int b = 0; b < 4; ++b) {
    const int gn = v0 + b * 16 + lr;
    if (gn >= NN) continue;
#pragma unroll
    for (int a = 0; a < 4; ++a) {
      const int n = n0 + a * 16 + lq * 4;
      f4 bb = *(const f4*)&bl1[n];
      bf4v pk;
      pk[0] = f2b(fmaxf(acc[a][b][0] + bb[0], 0.f));
      pk[1] = f2b(fmaxf(acc[a][b][1] + bb[1], 0.f));
      pk[2] = f2b(fmaxf(acc[a][b][2] + bb[2], 0.f));
      pk[3] = f2b(fmaxf(acc[a][b][3] + bb[3], 0.f));
      *(bf4v*)&h1b[(size_t)gn * 256 + n] = pk;
    }
  }
}

// ---------------- final linear: out = concat(h1b, s2/cnt) @ Wl2 + bl2 ---------

__global__ __launch_bounds__(256) void out_k(
    const short* __restrict__ h1b, const float* __restrict__ s2,
    const int* __restrict__ cnt, const float* __restrict__ Wl2,
    const float* __restrict__ bl2, float* __restrict__ out)
{
  __shared__ float A8[8][512];
  const int n0 = blockIdx.x * 8;
  const int tx = threadIdx.x;
  const int ty = threadIdx.y;
  const int t = ty * 32 + tx;
  const int row = t >> 5;
  const int k0 = (t & 31) * 16;
  const int n = n0 + row;
  const float inv = 1.0f / fmaxf((float)cnt[n], 1.0f);
#pragma unroll
  for (int i = 0; i < 16; i += 4) {
    int k = k0 + i;
    f4 v;
    if (k < 256) {
      v = b2f4(*(const bf4v*)&h1b[(size_t)n * 256 + k]);
    } else {
      v = *(const f4*)&s2[(size_t)n * 256 + (k - 256)];
      v[0] *= inv; v[1] *= inv; v[2] *= inv; v[3] *= inv;
    }
    *(f4*)&A8[row][k] = v;
  }
  __syncthreads();
  float acc = bl2[tx];
#pragma unroll 8
  for (int k = 0; k < 512; k++) acc = fmaf(A8[ty][k], Wl2[(size_t)k * 32 + tx], acc);
  out[(size_t)(n0 + ty) * 32 + tx] = acc;
}

// ---------------- launch ------------------------------------------------------

extern "C" void kernel_launch(void* const* d_in, const int* in_sizes, int n_in,
                              void* d_out, int out_size, void* d_ws, size_t ws_size,
                              hipStream_t stream) {
  const float* nf   = (const float*)d_in[0];
  const float* ef   = (const float*)d_in[1];
  const int*   src  = (const int*)d_in[2];
  const int*   dst  = (const int*)d_in[3];
  const float* We1  = (const float*)d_in[4];
  const float* be1  = (const float*)d_in[5];
  const float* Wr1a = (const float*)d_in[6];
  const float* br1a = (const float*)d_in[7];
  const float* Wr1b = (const float*)d_in[8];
  const float* br1b = (const float*)d_in[9];
  const float* Wl1  = (const float*)d_in[10];
  const float* bl1  = (const float*)d_in[11];
  const float* We2  = (const float*)d_in[12];
  const float* be2  = (const float*)d_in[13];
  const float* Wr2a = (const float*)d_in[14];
  const float* br2a = (const float*)d_in[15];
  const float* Wr2b = (const float*)d_in[16];
  const float* br2b = (const float*)d_in[17];
  const float* Wl2  = (const float*)d_in[18];
  const float* bl2  = (const float*)d_in[19];

  float* ws = (float*)d_ws;
  float* s1   = ws;                             // N*128 f
  float* s2   = s1 + (size_t)NN * 128;          // N*256 f
  int*   cnt  = (int*)(s2 + (size_t)NN * 256);  // N
  short* h1b  = (short*)(cnt + NN);             // N*256 bf16
  short* nfb  = h1b + (size_t)NN * 256;         // N*128 bf16
  short* WaT1 = nfb + (size_t)NN * 128;         // 128*128 bf16
  short* WbT1 = WaT1 + 128 * 128;               // 128*128
  short* We2T = WbT1 + 128 * 128;               // 256*128
  short* WaT2 = We2T + 256 * 128;               // 256*256
  short* WbT2 = WaT2 + 256 * 256;               // 256*256
  short* Wl1T = WbT2 + 256 * 256;               // 256*256
  int*   off2 = (int*)(Wl1T + 256 * 256);       // N
  int*   perm = off2 + NN;                      // E
  int*   dsts = perm + NE;                      // E
  float* invn1 = (float*)(dsts + NE);           // N
  float* invn2 = invn1 + NN;                    // N

  size_t need = ((size_t)NN * 128 + (size_t)NN * 256 + NN) * 4 +
                ((size_t)NN * 256 + (size_t)NN * 128 +
                 (size_t)128 * 128 * 2 + (size_t)256 * 128 +
                 (size_t)256 * 256 * 3) * 2 +
                ((size_t)NN + 2 * (size_t)NE + 2 * (size_t)NN) * 4;
  if (ws_size < need) return;

  // weight transpose+convert and nf convert (tiny)
  wt_k<<<(128 * 128 + 255) / 256, 256, 0, stream>>>(Wr1a, WaT1, 128, 128);
  wt_k<<<(128 * 128 + 255) / 256, 256, 0, stream>>>(Wr1b, WbT1, 128, 128);
  wt_k<<<(128 * 256 + 255) / 256, 256, 0, stream>>>(We2, We2T, 128, 256);
  wt_k<<<(256 * 256 + 255) / 256, 256, 0, stream>>>(Wr2a, WaT2, 256, 256);
  wt_k<<<(256 * 256 + 255) / 256, 256, 0, stream>>>(Wr2b, WbT2, 256, 256);
  wt_k<<<(256 * 256 + 255) / 256, 256, 0, stream>>>(Wl1, Wl1T, 256, 256);
  cvt_k<<<(NN * 128 / 4 + 255) / 256, 256, 0, stream>>>(nf, nfb, NN * 128 / 4);
  norm1_k<<<(NN + 3) / 4, 256, 0, stream>>>(nfb, invn1);

  // zero s1, s2, cnt (contiguous)
  hipMemsetAsync(s1, 0, ((size_t)NN * 128 + (size_t)NN * 256 + NN) * 4, stream);

  cnt_k<<<NE / 256, 256, 0, stream>>>(dst, cnt);

  // counting sort by dst
  scan_k<<<1, 1024, 0, stream>>>(cnt, off2);
  perm_k<<<NE / 256, 256, 0, stream>>>(dst, off2, perm, dsts);

  edge_mlp1<<<NE / 64, 256, 0, stream>>>(nfb, ef, src, perm, dsts, invn1,
                                         We1, be1, WaT1, br1a, WbT1, br1b, s1);

  h1m_k<<<(NN + 63) / 64, 256, 0, stream>>>(nf, s1, cnt, Wl1T, bl1, h1b);
  norm2_k<<<(NN + 3) / 4, 256, 0, stream>>>(h1b, invn2);

  edge_mlp2<<<NE / 64, 256, 0, stream>>>(h1b, ef, src, perm, dsts, invn2,
                                         We1, be1, We2T, be2, WaT2, br2a,
                                         WbT2, br2b, s2);

  out_k<<<NN / 8, dim3(32, 8), 0, stream>>>(h1b, s2, cnt, Wl2, bl2, (float*)d_out);
}